// Round 7
// baseline (1138.461 us; speedup 1.0000x reference)
//
#include <hip/hip_runtime.h>
#include <stdint.h>
#include <float.h>

// B=2, L=2048, E=1024, H=16, Dk=Dv=64, top_k=32, temperature=0.7
constexpr int L = 2048;
constexpr int H = 16;
constexpr float SCALE = 0.17857142857142858f;   // 1/(sqrt(64)*0.7) (bf16 copy only)
constexpr int OUT0 = 2 * 2048 * 64;             // output floats; probs follow in d_out

typedef float f32x4 __attribute__((ext_vector_type(4)));
typedef short s16x8 __attribute__((ext_vector_type(8)));
typedef unsigned short u16x8 __attribute__((ext_vector_type(8)));

__device__ __forceinline__ float wave_fmax(float x) {
#pragma unroll
  for (int s = 32; s; s >>= 1) x = fmaxf(x, __shfl_xor(x, s));
  return x;
}
__device__ __forceinline__ float wave_fsum(float x) {
#pragma unroll
  for (int s = 32; s; s >>= 1) x += __shfl_xor(x, s);
  return x;
}
__device__ __forceinline__ int wave_isum(int x) {
#pragma unroll
  for (int s = 32; s; s >>= 1) x += __shfl_xor(x, s);
  return x;
}
__device__ __forceinline__ unsigned f2sort(float f) {
  unsigned u = __float_as_uint(f);
  return (u & 0x80000000u) ? ~u : (u | 0x80000000u);
}
__device__ __forceinline__ void lds_fence() {
  __asm__ __volatile__("s_waitcnt lgkmcnt(0)" ::: "memory");
}
__device__ __forceinline__ unsigned short rne_bf16(float f) {
  unsigned u = __float_as_uint(f);
  return (unsigned short)((u + 0x7fffu + ((u >> 16) & 1u)) >> 16);
}

// ---------------- Projection GEMM: Y[b][h][l][d] = sum_e X[m][e] * W[h*64+d][e]  (fp32, UNSCALED)
// Tile 128(m) x 64(n), micro 8x4, BK=32, double-buffered LDS, register prefetch.
// Per-element k-accumulation order identical to previous rounds (bit-exact).
template <int K, bool EMIT>
__global__ __launch_bounds__(256) void proj_kernel(const float* __restrict__ X,
                                                   const float* __restrict__ W,
                                                   float* __restrict__ Y,
                                                   unsigned short* __restrict__ Yb,
                                                   float bscale) {
  __shared__ float As[2][32][128];   // 32 KB
  __shared__ float Bs[2][32][64];    // 16 KB
  const int t = threadIdx.x;
  const int tx = t & 15;             // n quad
  const int ty = t >> 4;             // m octet
  const int m0 = blockIdx.y * 128;
  const int n0 = blockIdx.x * 64;
  const int ar = t >> 1, ac = (t & 1) * 16;   // A: 16 consecutive k per thread
  const int br = t >> 2, bc = (t & 3) * 8;    // B: 8 consecutive k per thread
  const float* xg = X + (size_t)(m0 + ar) * K + ac;
  const float* wg = W + (size_t)(n0 + br) * K + bc;

  float4 a0, a1, a2, a3, b0, b1;
  a0 = *(const float4*)(xg + 0);
  a1 = *(const float4*)(xg + 4);
  a2 = *(const float4*)(xg + 8);
  a3 = *(const float4*)(xg + 12);
  b0 = *(const float4*)(wg + 0);
  b1 = *(const float4*)(wg + 4);
  {
    float ab[16] = {a0.x, a0.y, a0.z, a0.w, a1.x, a1.y, a1.z, a1.w,
                    a2.x, a2.y, a2.z, a2.w, a3.x, a3.y, a3.z, a3.w};
#pragma unroll
    for (int i = 0; i < 16; ++i) As[0][ac + i][ar] = ab[i];
    float bb[8] = {b0.x, b0.y, b0.z, b0.w, b1.x, b1.y, b1.z, b1.w};
#pragma unroll
    for (int i = 0; i < 8; ++i) Bs[0][bc + i][br] = bb[i];
  }
  __syncthreads();

  float acc[8][4] = {};
  constexpr int C = K / 32;
  int buf = 0;
#pragma unroll 1
  for (int c = 0; c < C; ++c) {
    if (c + 1 < C) {
      const float* xn = xg + (c + 1) * 32;
      const float* wn = wg + (c + 1) * 32;
      a0 = *(const float4*)(xn + 0);
      a1 = *(const float4*)(xn + 4);
      a2 = *(const float4*)(xn + 8);
      a3 = *(const float4*)(xn + 12);
      b0 = *(const float4*)(wn + 0);
      b1 = *(const float4*)(wn + 4);
    }
#pragma unroll
    for (int kk = 0; kk < 32; ++kk) {
      float4 av0 = *(const float4*)&As[buf][kk][ty * 8];
      float4 av1 = *(const float4*)&As[buf][kk][ty * 8 + 4];
      float4 bv = *(const float4*)&Bs[buf][kk][tx * 4];
      float ar8[8] = {av0.x, av0.y, av0.z, av0.w, av1.x, av1.y, av1.z, av1.w};
      float br4[4] = {bv.x, bv.y, bv.z, bv.w};
#pragma unroll
      for (int i = 0; i < 8; ++i)
#pragma unroll
        for (int j = 0; j < 4; ++j) acc[i][j] = fmaf(ar8[i], br4[j], acc[i][j]);
    }
    if (c + 1 < C) {
      int nb = buf ^ 1;
      float ab[16] = {a0.x, a0.y, a0.z, a0.w, a1.x, a1.y, a1.z, a1.w,
                      a2.x, a2.y, a2.z, a2.w, a3.x, a3.y, a3.z, a3.w};
#pragma unroll
      for (int i = 0; i < 16; ++i) As[nb][ac + i][ar] = ab[i];
      float bb[8] = {b0.x, b0.y, b0.z, b0.w, b1.x, b1.y, b1.z, b1.w};
#pragma unroll
      for (int i = 0; i < 8; ++i) Bs[nb][bc + i][br] = bb[i];
      __syncthreads();
      buf = nb;
    }
  }

  const int n = n0 + tx * 4;
  const int h = n >> 6, d = n & 63;
#pragma unroll
  for (int i = 0; i < 8; ++i) {
    int mm = m0 + ty * 8 + i;
    int b = mm >> 11, l = mm & 2047;
    size_t off = (((size_t)b * H + h) * L + l) * 64 + d;
    *(float4*)&Y[off] = make_float4(acc[i][0], acc[i][1], acc[i][2], acc[i][3]);
    if (EMIT) {
      ushort4 bv4;
      bv4.x = rne_bf16(acc[i][0] * bscale);
      bv4.y = rne_bf16(acc[i][1] * bscale);
      bv4.z = rne_bf16(acc[i][2] * bscale);
      bv4.w = rne_bf16(acc[i][3] * bscale);
      *(ushort4*)&Yb[off] = bv4;
    }
  }
}

// ---------------- Approx logits, bf16 MFMA: AL[bh][i][j] = bf16(dot64(qb[i], kb[j]))
// Block = 128x128 tile, 4 waves in 2x2, K=64 via 2x mfma_16x16x32.
constexpr int ALD = 72;    // padded LDS stride (bf16 units) for frag reads
constexpr int CTD = 136;   // padded LDS stride for output transpose (272 B = 17x16B)

__global__ __launch_bounds__(256) void alogits_kernel(const unsigned short* __restrict__ Qb,
                                                      const unsigned short* __restrict__ Kb,
                                                      unsigned short* __restrict__ AL) {
  __shared__ union {
    unsigned short qk[2][128 * ALD];   // 36864 B
    unsigned short ct[128 * CTD];      // 34816 B
  } sh;
  const int t = threadIdx.x;
  const int bh = blockIdx.z;
  const int m0 = blockIdx.y * 128, n0 = blockIdx.x * 128;
  const unsigned short* Qg = Qb + (size_t)bh * L * 64 + (size_t)m0 * 64;
  const unsigned short* Kg = Kb + (size_t)bh * L * 64 + (size_t)n0 * 64;
#pragma unroll
  for (int i = 0; i < 4; ++i) {
    int blk = t * 4 + i;               // 0..1023 : 128 rows x 8 blocks(16B)
    int r = blk >> 3, lb = blk & 7;
    *(u16x8*)&sh.qk[0][r * ALD + lb * 8] = *(const u16x8*)&Qg[r * 64 + lb * 8];
    *(u16x8*)&sh.qk[1][r * ALD + lb * 8] = *(const u16x8*)&Kg[r * 64 + lb * 8];
  }
  __syncthreads();
  const int wv = t >> 6, lane = t & 63;
  const int wm = (wv & 1) * 64, wn = (wv >> 1) * 64;
  const int fr = lane & 15, quad = lane >> 4;
  f32x4 acc[16];
#pragma unroll
  for (int i = 0; i < 16; ++i) acc[i] = (f32x4){0.f, 0.f, 0.f, 0.f};
#pragma unroll
  for (int kh = 0; kh < 2; ++kh) {
    s16x8 a[4], b[4];
#pragma unroll
    for (int mi = 0; mi < 4; ++mi)
      a[mi] = *(const s16x8*)&sh.qk[0][(wm + mi * 16 + fr) * ALD + kh * 32 + quad * 8];
#pragma unroll
    for (int ni = 0; ni < 4; ++ni)
      b[ni] = *(const s16x8*)&sh.qk[1][(wn + ni * 16 + fr) * ALD + kh * 32 + quad * 8];
#pragma unroll
    for (int mi = 0; mi < 4; ++mi)
#pragma unroll
      for (int ni = 0; ni < 4; ++ni)
        acc[mi * 4 + ni] = __builtin_amdgcn_mfma_f32_16x16x32_bf16(
            a[mi], b[ni], acc[mi * 4 + ni], 0, 0, 0);
  }
  __syncthreads();                                           // reuse LDS as CT
#pragma unroll
  for (int mi = 0; mi < 4; ++mi)
#pragma unroll
    for (int ni = 0; ni < 4; ++ni) {
      int col = wn + ni * 16 + fr;
#pragma unroll
      for (int r = 0; r < 4; ++r) {
        int rowl = wm + mi * 16 + quad * 4 + r;
        sh.ct[rowl * CTD + col] = rne_bf16(acc[mi * 4 + ni][r]);
      }
    }
  __syncthreads();
  // Coalesced NT store: each 16-lane quarter writes one contiguous 256 B row
  // slice (4 full 64B lines) -> no partial-line write amplification.
  unsigned short* Abase = AL + (size_t)bh * L * L;
  const int rq = lane >> 4;            // 0..3 row within group-of-4
  const int cq = (lane & 15) * 8;      // 0..120 col (16B chunks)
#pragma unroll
  for (int it = 0; it < 8; ++it) {
    int row = wv * 32 + it * 4 + rq;
    u16x8 v8 = *(const u16x8*)&sh.ct[row * CTD + cq];
    __builtin_nontemporal_store(v8, (u16x8*)&Abase[(size_t)(m0 + row) * L + n0 + cq]);
  }
}

// ---------------- Select: approx top-k filter -> exact fp32 recompute -> softmax -> probs + PV
// One wave per row; lane owns approx slots j = u*64 + lane.
__global__ __launch_bounds__(256) void select_kernel(const unsigned short* __restrict__ AL,
                                                     const float* __restrict__ Qp,
                                                     const float* __restrict__ Kp,
                                                     const float* __restrict__ Vp,
                                                     float* __restrict__ Probs,
                                                     float* __restrict__ Mixed) {
  __shared__ float prow[4][2048];
  __shared__ float qbuf[4][64];
  __shared__ float cbuf[4][64];
  __shared__ int ibufc[4][64];
  __shared__ float pbuf[4][32];
  __shared__ int ibuf[4][32];
  const int lane = threadIdx.x & 63;
  const int w = threadIdx.x >> 6;
  const int row = blockIdx.x * 4 + w;
  const int bh = row >> 11;
  const int q = row & 2047;
  const unsigned long long below = (lane == 63) ? 0x7fffffffffffffffull
                                                : ((1ull << lane) - 1ull);
  const unsigned short* Arow = AL + (size_t)row * 2048;

  float lg[32];
#pragma unroll
  for (int u = 0; u < 32; ++u) {
    unsigned us = __builtin_nontemporal_load(Arow + u * 64 + lane);
    lg[u] = __uint_as_float(us << 16);
  }
  // zero prow early (wave-local)
#pragma unroll
  for (int u = 0; u < 32; ++u) prow[w][u * 64 + lane] = 0.f;
  // stage fp32 Q row (unscaled)
  if (lane < 16)
    *(float4*)&qbuf[w][lane * 4] = *(const float4*)&Qp[((size_t)bh * L + q) * 64 + lane * 4];

  float m = lg[0];
#pragma unroll
  for (int u = 1; u < 32; ++u) m = fmaxf(m, lg[u]);
  m = wave_fmax(m);

  // ---- T32a = 32nd-largest approx value (bit-exact on approx)
  float T = 0.f;
  bool found = false;
  float cut = m - 2.2f;
  float lo = 0.f, hi = m;
  bool has_lo = false;
  for (int attempt = 0; attempt < 8 && !found; ++attempt) {
    int c = 0;
#pragma unroll
    for (int u = 0; u < 32; ++u) c += (lg[u] > cut) ? 1 : 0;
    c = wave_isum(c);
    if (c < 32) {
      hi = cut;
      cut = has_lo ? 0.5f * (lo + cut) : (cut - 0.45f);
    } else if (c > 64) {
      lo = cut; has_lo = true;
      cut = 0.5f * (cut + hi);
    } else {
      int base = 0;
#pragma unroll
      for (int u = 0; u < 32; ++u) {
        bool cd = lg[u] > cut;
        unsigned long long mk = __ballot(cd);
        if (cd) cbuf[w][base + __popcll(mk & below)] = lg[u];
        base += __popcll(mk);
      }
      lds_fence();
      float v2 = (lane < c) ? cbuf[w][lane] : -FLT_MAX;
#pragma unroll
      for (int size = 2; size <= 64; size <<= 1)
#pragma unroll
        for (int stride = size >> 1; stride; stride >>= 1) {
          float pv = __shfl_xor(v2, stride);
          bool lower = (lane & stride) == 0;
          bool asc = (lane & size) == 0;
          v2 = (lower == asc) ? fminf(v2, pv) : fmaxf(v2, pv);
        }
      T = __shfl(v2, 32);
      found = true;
    }
  }
  if (!found) {   // exact radix bisect on approx bits
    unsigned tb = 0;
    for (int bit = 31; bit >= 0; --bit) {
      unsigned cand = tb | (1u << bit);
      int c = 0;
#pragma unroll
      for (int u = 0; u < 32; ++u) c += (f2sort(lg[u]) >= cand) ? 1 : 0;
      c = wave_isum(c);
      if (c >= 32) tb = cand;
    }
    T = (tb & 0x80000000u) ? __uint_as_float(tb & 0x7fffffffu) : __uint_as_float(~tb);
  }

  // ---- candidate set: largest margin whose count fits the 64 recompute slots
  float theta = T;
  int c2 = 0;
  const float margs[5] = {0.40f, 0.25f, 0.15f, 0.08f, 0.0f};
#pragma unroll
  for (int a = 0; a < 5; ++a) {
    float th = T - margs[a];
    int c = 0;
#pragma unroll
    for (int u = 0; u < 32; ++u) c += (lg[u] >= th) ? 1 : 0;
    c = wave_isum(c);
    theta = th; c2 = c;
    if (c <= 64) break;
  }
  if (c2 > 64) c2 = 64;   // astronomically unlikely tie flood

  // rank-scatter candidate indices in (u,lane)=flat-j order
  {
    int base = 0;
#pragma unroll
    for (int u = 0; u < 32; ++u) {
      bool cd = lg[u] >= theta;
      unsigned long long mk = __ballot(cd);
      if (cd) {
        int s = base + __popcll(mk & below);
        if (s < 64) ibufc[w][s] = u * 64 + lane;
      }
      base += __popcll(mk);
    }
  }
  lds_fence();

  // ---- exact fp32 recompute for candidates (one per lane)
  int myi = (lane < c2) ? ibufc[w][lane] : 0x7fffffff;
  float vex = -FLT_MAX;
  if (lane < c2) {
    const float4* K4 = (const float4*)(Kp + ((size_t)bh * L + myi) * 64);
    const float4* Q4 = (const float4*)&qbuf[w][0];
    float acc = 0.f;
#pragma unroll
    for (int dq = 0; dq < 16; ++dq) {
      float4 kv = K4[dq];
      float4 qv = Q4[dq];
      acc = fmaf(qv.x, kv.x, acc);
      acc = fmaf(qv.y, kv.y, acc);
      acc = fmaf(qv.z, kv.z, acc);
      acc = fmaf(qv.w, kv.w, acc);
    }
    vex = (acc * 0.125f) / 0.7f;   // matches ref: (q/8)@k then /0.7
  }

  // ---- sort 64 lanes by (value desc, index asc): key ascending
  unsigned long long key = ((unsigned long long)(~f2sort(vex)) << 32) | (unsigned)myi;
#pragma unroll
  for (int size = 2; size <= 64; size <<= 1)
#pragma unroll
    for (int stride = size >> 1; stride; stride >>= 1) {
      unsigned long long pk = __shfl_xor(key, stride);
      unsigned long long mn = key < pk ? key : pk;
      unsigned long long mx = key < pk ? pk : key;
      bool keepmin = ((lane & stride) == 0) == ((lane & size) == 0);
      key = keepmin ? mn : mx;
    }
  unsigned uv = ~(unsigned)(key >> 32);
  float vs = __uint_as_float((uv & 0x80000000u) ? (uv & 0x7fffffffu) : ~uv);
  int sidx = (int)(unsigned)(key & 0xffffffffull);

  // ---- softmax over kept 32 (lanes 0..31 sorted best-first)
  float vmax = __shfl(vs, 0);
  float e = (lane < 32) ? __expf(vs - vmax) : 0.f;
  float S = wave_fsum(e);
  float p = e / S;
  if (lane < 32) {
    pbuf[w][lane] = p;
    ibuf[w][lane] = sidx;
    prow[w][sidx] = p;
  }
  lds_fence();

  // ---- dense probs row write (zeros + 32 kept)
  float* Prow = Probs + (size_t)row * 2048;
#pragma unroll
  for (int u = 0; u < 32; ++u)
    __builtin_nontemporal_store(prow[w][u * 64 + lane], Prow + u * 64 + lane);

  // ---- sparse PV
  const float* Vb = Vp + (size_t)bh * L * 64;
  float accv = 0.f;
#pragma unroll
  for (int i = 0; i < 32; ++i)
    accv = fmaf(pbuf[w][i], Vb[(size_t)ibuf[w][i] * 64 + lane], accv);
  const int bb = bh >> 4, hh = bh & 15;
  Mixed[((size_t)(bb * 2048 + q)) * 1024 + hh * 64 + lane] = accv;
}

// ---------------- Output FC: Out[m][n] = sum_k Mixed[m][k] * Wfc[n][k]  (M=4096,N=64,K=1024)
__global__ __launch_bounds__(256) void fc_kernel(const float* __restrict__ Mx,
                                                 const float* __restrict__ Wfc,
                                                 float* __restrict__ Out) {
  __shared__ float As[32][64];
  __shared__ float Ws[64][64];
  const int t = threadIdx.x;
  const int tx = t & 15;
  const int ty = t >> 4;
  const int m0 = blockIdx.x * 32;
  float acc[2][4] = {};
  for (int k0 = 0; k0 < 1024; k0 += 64) {
    __syncthreads();
    {
      int lin = t * 8;
      int rr = lin >> 6, kk = lin & 63;
      *(float4*)&As[rr][kk] = *(const float4*)&Mx[(size_t)(m0 + rr) * 1024 + k0 + kk];
      *(float4*)&As[rr][kk + 4] = *(const float4*)&Mx[(size_t)(m0 + rr) * 1024 + k0 + kk + 4];
    }
    {
      int n = t >> 2;
      int kq = (t & 3) * 16;
#pragma unroll
      for (int u = 0; u < 4; ++u) {
        float4 wv = *(const float4*)&Wfc[(size_t)n * 1024 + k0 + kq + u * 4];
        Ws[kq + u * 4 + 0][n] = wv.x;
        Ws[kq + u * 4 + 1][n] = wv.y;
        Ws[kq + u * 4 + 2][n] = wv.z;
        Ws[kq + u * 4 + 3][n] = wv.w;
      }
    }
    __syncthreads();
#pragma unroll
    for (int kk = 0; kk < 64; ++kk) {
      float a0 = As[ty][kk], a1 = As[ty + 16][kk];
      float4 wv = *(const float4*)&Ws[kk][tx * 4];
      float wr[4] = {wv.x, wv.y, wv.z, wv.w};
#pragma unroll
      for (int j = 0; j < 4; ++j) {
        acc[0][j] = fmaf(a0, wr[j], acc[0][j]);
        acc[1][j] = fmaf(a1, wr[j], acc[1][j]);
      }
    }
  }
#pragma unroll
  for (int i = 0; i < 2; ++i) {
    int mm = m0 + ty + i * 16;
    *(float4*)&Out[(size_t)mm * 64 + tx * 4] =
        make_float4(acc[i][0], acc[i][1], acc[i][2], acc[i][3]);
  }
}

extern "C" void kernel_launch(void* const* d_in, const int* in_sizes, int n_in,
                              void* d_out, int out_size, void* d_ws, size_t ws_size,
                              hipStream_t stream) {
  const float* q    = (const float*)d_in[0];
  const float* k    = (const float*)d_in[1];
  const float* v    = (const float*)d_in[2];
  const float* w_q  = (const float*)d_in[3];
  const float* w_k  = (const float*)d_in[4];
  const float* w_v  = (const float*)d_in[5];
  const float* w_fc = (const float*)d_in[6];

  float* out = (float*)d_out;
  float* probs = out + OUT0;

  float* ws = (float*)d_ws;
  float* q_proj = ws;                          // [B][H][L][64] fp32 (UNSCALED)
  float* k_proj = ws + 4194304;
  float* v_proj = ws + 8388608;
  float* mixed  = ws + 12582912;               // [B*L][1024]
  unsigned short* qb = (unsigned short*)(ws + 16777216);   // bf16(q_proj*SCALE)
  unsigned short* kb = (unsigned short*)(ws + 18874368);   // bf16(k_proj)
  unsigned short* al = (unsigned short*)(ws + 20971520);   // approx logits bf16 [bh][i][j]

  dim3 blk(256);
  proj_kernel<1024, true><<<dim3(16, 32), blk, 0, stream>>>(q, w_q, q_proj, qb, SCALE);
  proj_kernel<1024, true><<<dim3(16, 32), blk, 0, stream>>>(k, w_k, k_proj, kb, 1.0f);
  proj_kernel<64, false><<<dim3(16, 32), blk, 0, stream>>>(v, w_v, v_proj, nullptr, 1.0f);
  alogits_kernel<<<dim3(16, 16, 32), blk, 0, stream>>>(qb, kb, al);
  select_kernel<<<dim3(16384), blk, 0, stream>>>(al, q_proj, k_proj, v_proj, probs, mixed);
  fc_kernel<<<dim3(128), blk, 0, stream>>>(mixed, w_fc, out);
}

// Round 8
// 1012.853 us; speedup vs baseline: 1.1240x; 1.1240x over previous
//
#include <hip/hip_runtime.h>
#include <stdint.h>
#include <float.h>

// B=2, L=2048, E=1024, H=16, Dk=Dv=64, top_k=32, temperature=0.7
constexpr int L = 2048;
constexpr int H = 16;
constexpr float SCALE = 0.17857142857142858f;   // 1/(sqrt(64)*0.7) (bf16 copy only)
constexpr int OUT0 = 2 * 2048 * 64;             // output floats; probs follow in d_out
constexpr float QSTEP = 0.0625f;                // int8 AL quant step (scale 16/unit)

typedef float f32x4 __attribute__((ext_vector_type(4)));
typedef short s16x8 __attribute__((ext_vector_type(8)));
typedef unsigned short u16x8 __attribute__((ext_vector_type(8)));

__device__ __forceinline__ float wave_fmax(float x) {
#pragma unroll
  for (int s = 32; s; s >>= 1) x = fmaxf(x, __shfl_xor(x, s));
  return x;
}
__device__ __forceinline__ float wave_fsum(float x) {
#pragma unroll
  for (int s = 32; s; s >>= 1) x += __shfl_xor(x, s);
  return x;
}
__device__ __forceinline__ int wave_isum(int x) {
#pragma unroll
  for (int s = 32; s; s >>= 1) x += __shfl_xor(x, s);
  return x;
}
__device__ __forceinline__ unsigned f2sort(float f) {
  unsigned u = __float_as_uint(f);
  return (u & 0x80000000u) ? ~u : (u | 0x80000000u);
}
__device__ __forceinline__ void lds_fence() {
  __asm__ __volatile__("s_waitcnt lgkmcnt(0)" ::: "memory");
}
__device__ __forceinline__ unsigned short rne_bf16(float f) {
  unsigned u = __float_as_uint(f);
  return (unsigned short)((u + 0x7fffu + ((u >> 16) & 1u)) >> 16);
}

// ---------------- Projection GEMM (R6 version — occupancy-friendly single buffer)
// Y[b][h][l][d] = sum_e X[m][e] * W[h*64+d][e]  (fp32, UNSCALED); optional bf16 copy.
template <int K, bool EMIT>
__global__ __launch_bounds__(256) void proj_kernel(const float* __restrict__ X,
                                                   const float* __restrict__ W,
                                                   float* __restrict__ Y,
                                                   unsigned short* __restrict__ Yb,
                                                   float bscale) {
  __shared__ float As[16][128];
  __shared__ float Bs[16][64];
  const int t = threadIdx.x;
  const int tx = t & 15;
  const int ty = t >> 4;
  const int m0 = blockIdx.y * 128;
  const int n0 = blockIdx.x * 64;
  const int ar = t >> 1, ac = (t & 1) * 8;
  const int br = t >> 2, bc = (t & 3) * 4;
  const float* xg = X + (size_t)(m0 + ar) * K + ac;
  const float* wg = W + (size_t)(n0 + br) * K + bc;
  float acc[8][4] = {};
  for (int k0 = 0; k0 < K; k0 += 16) {
    float4 a0 = *(const float4*)(xg + k0);
    float4 a1 = *(const float4*)(xg + k0 + 4);
    float4 b0 = *(const float4*)(wg + k0);
    __syncthreads();
    As[ac + 0][ar] = a0.x; As[ac + 1][ar] = a0.y; As[ac + 2][ar] = a0.z; As[ac + 3][ar] = a0.w;
    As[ac + 4][ar] = a1.x; As[ac + 5][ar] = a1.y; As[ac + 6][ar] = a1.z; As[ac + 7][ar] = a1.w;
    Bs[bc + 0][br] = b0.x; Bs[bc + 1][br] = b0.y; Bs[bc + 2][br] = b0.z; Bs[bc + 3][br] = b0.w;
    __syncthreads();
#pragma unroll
    for (int kk = 0; kk < 16; ++kk) {
      float4 av0 = *(const float4*)&As[kk][ty * 8];
      float4 av1 = *(const float4*)&As[kk][ty * 8 + 4];
      float4 bv = *(const float4*)&Bs[kk][tx * 4];
      float ar8[8] = {av0.x, av0.y, av0.z, av0.w, av1.x, av1.y, av1.z, av1.w};
      float br4[4] = {bv.x, bv.y, bv.z, bv.w};
#pragma unroll
      for (int i = 0; i < 8; ++i)
#pragma unroll
        for (int j = 0; j < 4; ++j) acc[i][j] = fmaf(ar8[i], br4[j], acc[i][j]);
    }
  }
  const int n = n0 + tx * 4;
  const int h = n >> 6, d = n & 63;
#pragma unroll
  for (int i = 0; i < 8; ++i) {
    int mm = m0 + ty * 8 + i;
    int b = mm >> 11, l = mm & 2047;
    size_t off = (((size_t)b * H + h) * L + l) * 64 + d;
    *(float4*)&Y[off] = make_float4(acc[i][0], acc[i][1], acc[i][2], acc[i][3]);
    if (EMIT) {
      ushort4 bv4;
      bv4.x = rne_bf16(acc[i][0] * bscale);
      bv4.y = rne_bf16(acc[i][1] * bscale);
      bv4.z = rne_bf16(acc[i][2] * bscale);
      bv4.w = rne_bf16(acc[i][3] * bscale);
      *(ushort4*)&Yb[off] = bv4;
    }
  }
}

// ---------------- Approx logits, bf16 MFMA -> int8 AL (scale 16, clamp +-127)
constexpr int ALD = 72;    // padded LDS stride (bf16 units) for frag reads
constexpr int CTB = 136;   // int8 CT stride in bytes (8-aligned, non-pow2)

__global__ __launch_bounds__(256) void alogits_kernel(const unsigned short* __restrict__ Qb,
                                                      const unsigned short* __restrict__ Kb,
                                                      char* __restrict__ AL) {
  __shared__ union {
    unsigned short qk[2][128 * ALD];   // 36864 B
    char ct[128 * CTB];                // 17408 B
  } sh;
  const int t = threadIdx.x;
  const int bh = blockIdx.z;
  const int m0 = blockIdx.y * 128, n0 = blockIdx.x * 128;
  const unsigned short* Qg = Qb + (size_t)bh * L * 64 + (size_t)m0 * 64;
  const unsigned short* Kg = Kb + (size_t)bh * L * 64 + (size_t)n0 * 64;
#pragma unroll
  for (int i = 0; i < 4; ++i) {
    int blk = t * 4 + i;               // 0..1023 : 128 rows x 8 blocks(16B)
    int r = blk >> 3, lb = blk & 7;
    *(u16x8*)&sh.qk[0][r * ALD + lb * 8] = *(const u16x8*)&Qg[r * 64 + lb * 8];
    *(u16x8*)&sh.qk[1][r * ALD + lb * 8] = *(const u16x8*)&Kg[r * 64 + lb * 8];
  }
  __syncthreads();
  const int wv = t >> 6, lane = t & 63;
  const int wm = (wv & 1) * 64, wn = (wv >> 1) * 64;
  const int fr = lane & 15, quad = lane >> 4;
  f32x4 acc[16];
#pragma unroll
  for (int i = 0; i < 16; ++i) acc[i] = (f32x4){0.f, 0.f, 0.f, 0.f};
#pragma unroll
  for (int kh = 0; kh < 2; ++kh) {
    s16x8 a[4], b[4];
#pragma unroll
    for (int mi = 0; mi < 4; ++mi)
      a[mi] = *(const s16x8*)&sh.qk[0][(wm + mi * 16 + fr) * ALD + kh * 32 + quad * 8];
#pragma unroll
    for (int ni = 0; ni < 4; ++ni)
      b[ni] = *(const s16x8*)&sh.qk[1][(wn + ni * 16 + fr) * ALD + kh * 32 + quad * 8];
#pragma unroll
    for (int mi = 0; mi < 4; ++mi)
#pragma unroll
      for (int ni = 0; ni < 4; ++ni)
        acc[mi * 4 + ni] = __builtin_amdgcn_mfma_f32_16x16x32_bf16(
            a[mi], b[ni], acc[mi * 4 + ni], 0, 0, 0);
  }
  __syncthreads();                                           // reuse LDS as CT
#pragma unroll
  for (int mi = 0; mi < 4; ++mi)
#pragma unroll
    for (int ni = 0; ni < 4; ++ni) {
      int col = wn + ni * 16 + fr;
#pragma unroll
      for (int r = 0; r < 4; ++r) {
        int rowl = wm + mi * 16 + quad * 4 + r;
        float sc = acc[mi * 4 + ni][r] * 16.0f;
        sc = fminf(fmaxf(sc, -127.0f), 127.0f);
        sh.ct[rowl * CTB + col] = (char)__float2int_rn(sc);
      }
    }
  __syncthreads();
  // Coalesced NT store: 16-lane quarter writes one contiguous 128 B row (2 full lines)
  char* Abase = AL + (size_t)bh * L * L;
  const int rq = lane >> 4;            // 0..3
  const int cq = (lane & 15) * 8;      // 0..120, 8 B per lane
#pragma unroll
  for (int it = 0; it < 8; ++it) {
    int row = wv * 32 + it * 4 + rq;
    uint2 v8 = *(const uint2*)&sh.ct[row * CTB + cq];
    __builtin_nontemporal_store(v8.x, (unsigned*)&Abase[(size_t)(m0 + row) * L + n0 + cq]);
    __builtin_nontemporal_store(v8.y, (unsigned*)&Abase[(size_t)(m0 + row) * L + n0 + cq + 4]);
  }
}

// ---------------- Select: int8 approx filter -> exact fp32 recompute -> softmax -> probs + PV
// One wave per row; lane owns keys (u2*64+lane)*4 + b  (u2=0..7, b=0..3).
__global__ __launch_bounds__(256) void select_kernel(const char* __restrict__ AL,
                                                     const float* __restrict__ Qp,
                                                     const float* __restrict__ Kp,
                                                     const float* __restrict__ Vp,
                                                     float* __restrict__ Probs,
                                                     float* __restrict__ Mixed) {
  __shared__ float prow[4][2048];
  __shared__ float qbuf[4][64];
  __shared__ float cbuf[4][64];
  __shared__ int ibufc[4][64];
  __shared__ float pbuf[4][32];
  __shared__ int ibuf[4][32];
  const int lane = threadIdx.x & 63;
  const int w = threadIdx.x >> 6;
  const int row = blockIdx.x * 4 + w;
  const int bh = row >> 11;
  const int q = row & 2047;
  const unsigned long long below = (lane == 63) ? 0x7fffffffffffffffull
                                                : ((1ull << lane) - 1ull);
  const unsigned* Arow = (const unsigned*)(AL + (size_t)row * 2048);

  float lg[32];
#pragma unroll
  for (int u2 = 0; u2 < 8; ++u2) {
    unsigned dw = __builtin_nontemporal_load(Arow + u2 * 64 + lane);
#pragma unroll
    for (int b = 0; b < 4; ++b)
      lg[u2 * 4 + b] = (float)((char)(dw >> (8 * b))) * QSTEP;
  }
  // zero prow early (wave-local)
#pragma unroll
  for (int u = 0; u < 32; ++u) prow[w][u * 64 + lane] = 0.f;
  // stage fp32 Q row (unscaled)
  if (lane < 16)
    *(float4*)&qbuf[w][lane * 4] = *(const float4*)&Qp[((size_t)bh * L + q) * 64 + lane * 4];

  float m = lg[0];
#pragma unroll
  for (int u = 1; u < 32; ++u) m = fmaxf(m, lg[u]);
  m = wave_fmax(m);

  // ---- T32a = 32nd-largest approx value (bit-exact on approx grid)
  float T = 0.f;
  bool found = false;
  float cut = m - 2.2f;
  float lo = 0.f, hi = m;
  bool has_lo = false;
  for (int attempt = 0; attempt < 8 && !found; ++attempt) {
    int c = 0;
#pragma unroll
    for (int u = 0; u < 32; ++u) c += (lg[u] > cut) ? 1 : 0;
    c = wave_isum(c);
    if (c < 32) {
      hi = cut;
      cut = has_lo ? 0.5f * (lo + cut) : (cut - 0.45f);
    } else if (c > 64) {
      lo = cut; has_lo = true;
      cut = 0.5f * (cut + hi);
    } else {
      int base = 0;                    // slot order arbitrary (set semantics)
#pragma unroll
      for (int u = 0; u < 32; ++u) {
        bool cd = lg[u] > cut;
        unsigned long long mk = __ballot(cd);
        if (cd) cbuf[w][base + __popcll(mk & below)] = lg[u];
        base += __popcll(mk);
      }
      lds_fence();
      float v2 = (lane < c) ? cbuf[w][lane] : -FLT_MAX;
#pragma unroll
      for (int size = 2; size <= 64; size <<= 1)
#pragma unroll
        for (int stride = size >> 1; stride; stride >>= 1) {
          float pv = __shfl_xor(v2, stride);
          bool lower = (lane & stride) == 0;
          bool asc = (lane & size) == 0;
          v2 = (lower == asc) ? fminf(v2, pv) : fmaxf(v2, pv);
        }
      T = __shfl(v2, 32);
      found = true;
    }
  }
  if (!found) {   // exact radix bisect on approx bits
    unsigned tb = 0;
    for (int bit = 31; bit >= 0; --bit) {
      unsigned cand = tb | (1u << bit);
      int c = 0;
#pragma unroll
      for (int u = 0; u < 32; ++u) c += (f2sort(lg[u]) >= cand) ? 1 : 0;
      c = wave_isum(c);
      if (c >= 32) tb = cand;
    }
    T = (tb & 0x80000000u) ? __uint_as_float(tb & 0x7fffffffu) : __uint_as_float(~tb);
  }

  // ---- candidate set: largest margin whose count fits the 64 recompute slots
  float theta = T;
  int c2 = 0;
  const float margs[5] = {0.40f, 0.25f, 0.15f, 0.08f, 0.0f};
#pragma unroll
  for (int a = 0; a < 5; ++a) {
    float th = T - margs[a];
    int c = 0;
#pragma unroll
    for (int u = 0; u < 32; ++u) c += (lg[u] >= th) ? 1 : 0;
    c = wave_isum(c);
    theta = th; c2 = c;
    if (c <= 64) break;
  }
  if (c2 > 64) c2 = 64;   // astronomically unlikely tie flood

  // rank-scatter candidate flat indices (slot order arbitrary)
  {
    int base = 0;
#pragma unroll
    for (int u = 0; u < 32; ++u) {
      bool cd = lg[u] >= theta;
      unsigned long long mk = __ballot(cd);
      if (cd) {
        int s = base + __popcll(mk & below);
        if (s < 64) ibufc[w][s] = ((u >> 2) * 64 + lane) * 4 + (u & 3);
      }
      base += __popcll(mk);
    }
  }
  lds_fence();

  // ---- exact fp32 recompute for candidates (one per lane)
  int myi = (lane < c2) ? ibufc[w][lane] : 0x7fffffff;
  float vex = -FLT_MAX;
  if (lane < c2) {
    const float4* K4 = (const float4*)(Kp + ((size_t)bh * L + myi) * 64);
    const float4* Q4 = (const float4*)&qbuf[w][0];
    float acc = 0.f;
#pragma unroll
    for (int dq = 0; dq < 16; ++dq) {
      float4 kv = K4[dq];
      float4 qv = Q4[dq];
      acc = fmaf(qv.x, kv.x, acc);
      acc = fmaf(qv.y, kv.y, acc);
      acc = fmaf(qv.z, kv.z, acc);
      acc = fmaf(qv.w, kv.w, acc);
    }
    vex = (acc * 0.125f) / 0.7f;   // matches ref: (q/8)@k then /0.7
  }

  // ---- sort 64 lanes by (value desc, index asc): key ascending
  unsigned long long key = ((unsigned long long)(~f2sort(vex)) << 32) | (unsigned)myi;
#pragma unroll
  for (int size = 2; size <= 64; size <<= 1)
#pragma unroll
    for (int stride = size >> 1; stride; stride >>= 1) {
      unsigned long long pk = __shfl_xor(key, stride);
      unsigned long long mn = key < pk ? key : pk;
      unsigned long long mx = key < pk ? pk : key;
      bool keepmin = ((lane & stride) == 0) == ((lane & size) == 0);
      key = keepmin ? mn : mx;
    }
  unsigned uv = ~(unsigned)(key >> 32);
  float vs = __uint_as_float((uv & 0x80000000u) ? (uv & 0x7fffffffu) : ~uv);
  int sidx = (int)(unsigned)(key & 0xffffffffull);

  // ---- softmax over kept 32 (lanes 0..31 sorted best-first)
  float vmax = __shfl(vs, 0);
  float e = (lane < 32) ? __expf(vs - vmax) : 0.f;
  float S = wave_fsum(e);
  float p = e / S;
  if (lane < 32) {
    pbuf[w][lane] = p;
    ibuf[w][lane] = sidx;
    prow[w][sidx] = p;
  }
  lds_fence();

  // ---- dense probs row write (zeros + 32 kept)
  float* Prow = Probs + (size_t)row * 2048;
#pragma unroll
  for (int u = 0; u < 32; ++u)
    __builtin_nontemporal_store(prow[w][u * 64 + lane], Prow + u * 64 + lane);

  // ---- sparse PV
  const float* Vb = Vp + (size_t)bh * L * 64;
  float accv = 0.f;
#pragma unroll
  for (int i = 0; i < 32; ++i)
    accv = fmaf(pbuf[w][i], Vb[(size_t)ibuf[w][i] * 64 + lane], accv);
  const int bb = bh >> 4, hh = bh & 15;
  Mixed[((size_t)(bb * 2048 + q)) * 1024 + hh * 64 + lane] = accv;
}

// ---------------- Output FC: Out[m][n] = sum_k Mixed[m][k] * Wfc[n][k]  (M=4096,N=64,K=1024)
__global__ __launch_bounds__(256) void fc_kernel(const float* __restrict__ Mx,
                                                 const float* __restrict__ Wfc,
                                                 float* __restrict__ Out) {
  __shared__ float As[32][64];
  __shared__ float Ws[64][64];
  const int t = threadIdx.x;
  const int tx = t & 15;
  const int ty = t >> 4;
  const int m0 = blockIdx.x * 32;
  float acc[2][4] = {};
  for (int k0 = 0; k0 < 1024; k0 += 64) {
    __syncthreads();
    {
      int lin = t * 8;
      int rr = lin >> 6, kk = lin & 63;
      *(float4*)&As[rr][kk] = *(const float4*)&Mx[(size_t)(m0 + rr) * 1024 + k0 + kk];
      *(float4*)&As[rr][kk + 4] = *(const float4*)&Mx[(size_t)(m0 + rr) * 1024 + k0 + kk + 4];
    }
    {
      int n = t >> 2;
      int kq = (t & 3) * 16;
#pragma unroll
      for (int u = 0; u < 4; ++u) {
        float4 wv = *(const float4*)&Wfc[(size_t)n * 1024 + k0 + kq + u * 4];
        Ws[kq + u * 4 + 0][n] = wv.x;
        Ws[kq + u * 4 + 1][n] = wv.y;
        Ws[kq + u * 4 + 2][n] = wv.z;
        Ws[kq + u * 4 + 3][n] = wv.w;
      }
    }
    __syncthreads();
#pragma unroll
    for (int kk = 0; kk < 64; ++kk) {
      float a0 = As[ty][kk], a1 = As[ty + 16][kk];
      float4 wv = *(const float4*)&Ws[kk][tx * 4];
      float wr[4] = {wv.x, wv.y, wv.z, wv.w};
#pragma unroll
      for (int j = 0; j < 4; ++j) {
        acc[0][j] = fmaf(a0, wr[j], acc[0][j]);
        acc[1][j] = fmaf(a1, wr[j], acc[1][j]);
      }
    }
  }
#pragma unroll
  for (int i = 0; i < 2; ++i) {
    int mm = m0 + ty + i * 16;
    *(float4*)&Out[(size_t)mm * 64 + tx * 4] =
        make_float4(acc[i][0], acc[i][1], acc[i][2], acc[i][3]);
  }
}

extern "C" void kernel_launch(void* const* d_in, const int* in_sizes, int n_in,
                              void* d_out, int out_size, void* d_ws, size_t ws_size,
                              hipStream_t stream) {
  const float* q    = (const float*)d_in[0];
  const float* k    = (const float*)d_in[1];
  const float* v    = (const float*)d_in[2];
  const float* w_q  = (const float*)d_in[3];
  const float* w_k  = (const float*)d_in[4];
  const float* w_v  = (const float*)d_in[5];
  const float* w_fc = (const float*)d_in[6];

  float* out = (float*)d_out;
  float* probs = out + OUT0;

  float* ws = (float*)d_ws;
  float* q_proj = ws;                          // [B][H][L][64] fp32 (UNSCALED)
  float* k_proj = ws + 4194304;
  float* v_proj = ws + 8388608;
  float* mixed  = ws + 12582912;               // [B*L][1024]
  unsigned short* qb = (unsigned short*)(ws + 16777216);   // bf16(q_proj*SCALE)
  unsigned short* kb = (unsigned short*)(ws + 18874368);   // bf16(k_proj)
  char* al = (char*)(ws + 20971520);           // approx logits int8 [bh][i][j], 128 MB

  dim3 blk(256);
  proj_kernel<1024, true><<<dim3(16, 32), blk, 0, stream>>>(q, w_q, q_proj, qb, SCALE);
  proj_kernel<1024, true><<<dim3(16, 32), blk, 0, stream>>>(k, w_k, k_proj, kb, 1.0f);
  proj_kernel<64, false><<<dim3(16, 32), blk, 0, stream>>>(v, w_v, v_proj, nullptr, 1.0f);
  alogits_kernel<<<dim3(16, 16, 32), blk, 0, stream>>>(qb, kb, al);
  select_kernel<<<dim3(16384), blk, 0, stream>>>(al, q_proj, k_proj, v_proj, probs, mixed);
  fc_kernel<<<dim3(128), blk, 0, stream>>>(mixed, w_fc, out);
}